// Round 1
// baseline (3903.041 us; speedup 1.0000x reference)
//
#include <hip/hip_runtime.h>
#include <cstdint>
#include <cstddef>

namespace {

constexpr int kNB   = 8;
constexpr int kN    = 4096;
constexpr int kS    = 1024;   // NPOINT
constexpr int kK    = 32;     // NSAMPLE
constexpr int kInCh = 64;
constexpr int kC0   = 67;     // 3 + 64
constexpr int kC0P  = 68;     // padded (zero col at c'=3)
constexpr int kC1   = 64;
constexpr int kC3   = 128;
constexpr int kRows = kNB * kS * kK;  // 262144
constexpr int kTileR = 128;
constexpr int kGemmBlocks = kRows / kTileR;  // 2048

// ---------------- Farthest point sampling -----------------------------------
// One block per batch. Bit-exact replication of the numpy reference:
// d = ((dx*dx + dy*dy) + dz*dz) with round-to-nearest ops (no FMA contraction),
// argmax = first occurrence of max.
__global__ __launch_bounds__(1024) void fps_kernel(const float* __restrict__ xyz,
                                                   float* __restrict__ newxyz) {
  __shared__ float sx[kN], sy[kN], sz[kN];
  __shared__ float red_v[16];
  __shared__ int   red_i[16];
  const int b = blockIdx.x;
  const int tid = threadIdx.x;
  const float* xb = xyz + (size_t)b * kN * 3;
  for (int i = tid; i < kN; i += 1024) {
    sx[i] = xb[i * 3 + 0];
    sy[i] = xb[i * 3 + 1];
    sz[i] = xb[i * 3 + 2];
  }
  __syncthreads();
  float px[4], py[4], pz[4], dist[4];
#pragma unroll
  for (int t = 0; t < 4; ++t) {
    const int i = tid + 1024 * t;
    px[t] = sx[i]; py[t] = sy[i]; pz[t] = sz[i];
    dist[t] = 1e10f;
  }
  float cx = sx[0], cy = sy[0], cz = sz[0];
  float* ob = newxyz + (size_t)b * kS * 3;
  if (tid == 0) { ob[0] = cx; ob[1] = cy; ob[2] = cz; }
  const int lane = tid & 63;
  const int wid  = tid >> 6;
  for (int j = 1; j < kS; ++j) {
    float bv = -1.0f; int bi = 0;
#pragma unroll
    for (int t = 0; t < 4; ++t) {
      const float dx = __fsub_rn(px[t], cx);
      const float dy = __fsub_rn(py[t], cy);
      const float dz = __fsub_rn(pz[t], cz);
      const float d0 = __fadd_rn(__fadd_rn(__fmul_rn(dx, dx), __fmul_rn(dy, dy)),
                                 __fmul_rn(dz, dz));
      const float d = fminf(dist[t], d0);
      dist[t] = d;
      if (d > bv) { bv = d; bi = tid + 1024 * t; }  // ascending index -> first max
    }
#pragma unroll
    for (int off = 1; off < 64; off <<= 1) {
      const float ov = __shfl_xor(bv, off, 64);
      const int   oi = __shfl_xor(bi, off, 64);
      if (ov > bv || (ov == bv && oi < bi)) { bv = ov; bi = oi; }
    }
    __syncthreads();   // previous iteration's red reads done
    if (lane == 0) { red_v[wid] = bv; red_i[wid] = bi; }
    __syncthreads();
    float fv = red_v[0]; int fi = red_i[0];
#pragma unroll
    for (int w = 1; w < 16; ++w) {
      const float v = red_v[w]; const int i2 = red_i[w];
      if (v > fv || (v == fv && i2 < fi)) { fv = v; fi = i2; }
    }
    cx = sx[fi]; cy = sy[fi]; cz = sz[fi];
    if (tid == 0) { ob[j * 3 + 0] = cx; ob[j * 3 + 1] = cy; ob[j * 3 + 2] = cz; }
  }
}

// ---------------- Ball query -------------------------------------------------
// One wave per query point; first-32 in-radius indices in ascending order,
// padded with the first index. Distance uses the reference's expanded form and
// the compare is done in double (python float radius*radius).
__global__ __launch_bounds__(256) void ballq_kernel(const float* __restrict__ xyz,
                                                    const float* __restrict__ newxyz,
                                                    int* __restrict__ gidx) {
  const int tid  = threadIdx.x;
  const int lane = tid & 63;
  const int gq   = blockIdx.x * 4 + (tid >> 6);
  const int b    = gq >> 10;
  const float* xb = xyz + (size_t)b * kN * 3;
  const float qx = newxyz[gq * 3 + 0];
  const float qy = newxyz[gq * 3 + 1];
  const float qz = newxyz[gq * 3 + 2];
  const float s2 = __fadd_rn(__fadd_rn(__fmul_rn(qx, qx), __fmul_rn(qy, qy)),
                             __fmul_rn(qz, qz));
  const double r2 = 0.2 * 0.2;
  int taken = 0;
  int first = 0;
  bool hasfirst = false;
  int* g = gidx + (size_t)gq * kK;
  for (int base = 0; base < kN; base += 64) {
    const int n = base + lane;
    const float fx = xb[n * 3 + 0], fy = xb[n * 3 + 1], fz = xb[n * 3 + 2];
    const float p2 = __fadd_rn(__fadd_rn(__fmul_rn(fx, fx), __fmul_rn(fy, fy)),
                               __fmul_rn(fz, fz));
    const float dt = __fadd_rn(__fadd_rn(__fmul_rn(qx, fx), __fmul_rn(qy, fy)),
                               __fmul_rn(qz, fz));
    const float d = __fadd_rn(__fadd_rn(__fmul_rn(-2.0f, dt), s2), p2);
    const bool in = !((double)d > r2);
    const unsigned long long m = __ballot(in);
    if (!hasfirst && m != 0ull) { first = base + __builtin_ctzll(m); hasfirst = true; }
    if (in) {
      const int pos = taken + (int)__popcll(m & ((1ull << lane) - 1ull));
      if (pos < kK) g[pos] = n;
    }
    taken += (int)__popcll(m);
    if (taken >= kK) break;
  }
  for (int p = taken + lane; p < kK; p += 64) g[p] = first;
}

// ---------------- GEMM core (shared pattern) ---------------------------------
// Block: 256 threads, tile 128 rows x 64 cols. Thread (tr = tid&15, tc = tid>>4)
// computes rows {tr+16i} x cols {tc*4+j}, acc[8][4].

template <int KDIM>
__device__ __forceinline__ void gemm_compute(const float xs[kTileR][kC0P],
                                             const float wl[kC1][kC0P],
                                             int tr, int tc, float acc[8][4]) {
#pragma unroll
  for (int i = 0; i < 8; ++i)
#pragma unroll
    for (int j = 0; j < 4; ++j) acc[i][j] = 0.0f;
#pragma unroll 4
  for (int c = 0; c < KDIM; c += 4) {
    const float4 wv0 = *(const float4*)&wl[tc * 4 + 0][c];
    const float4 wv1 = *(const float4*)&wl[tc * 4 + 1][c];
    const float4 wv2 = *(const float4*)&wl[tc * 4 + 2][c];
    const float4 wv3 = *(const float4*)&wl[tc * 4 + 3][c];
#pragma unroll
    for (int i = 0; i < 8; ++i) {
      const float4 xv = *(const float4*)&xs[tr + 16 * i][c];
      acc[i][0] = fmaf(xv.x, wv0.x, acc[i][0]);
      acc[i][0] = fmaf(xv.y, wv0.y, acc[i][0]);
      acc[i][0] = fmaf(xv.z, wv0.z, acc[i][0]);
      acc[i][0] = fmaf(xv.w, wv0.w, acc[i][0]);
      acc[i][1] = fmaf(xv.x, wv1.x, acc[i][1]);
      acc[i][1] = fmaf(xv.y, wv1.y, acc[i][1]);
      acc[i][1] = fmaf(xv.z, wv1.z, acc[i][1]);
      acc[i][1] = fmaf(xv.w, wv1.w, acc[i][1]);
      acc[i][2] = fmaf(xv.x, wv2.x, acc[i][2]);
      acc[i][2] = fmaf(xv.y, wv2.y, acc[i][2]);
      acc[i][2] = fmaf(xv.z, wv2.z, acc[i][2]);
      acc[i][2] = fmaf(xv.w, wv2.w, acc[i][2]);
      acc[i][3] = fmaf(xv.x, wv3.x, acc[i][3]);
      acc[i][3] = fmaf(xv.y, wv3.y, acc[i][3]);
      acc[i][3] = fmaf(xv.z, wv3.z, acc[i][3]);
      acc[i][3] = fmaf(xv.w, wv3.w, acc[i][3]);
    }
  }
}

// Epilogue: add bias, write y, and per-channel {sum, sumsq} partials.
__device__ __forceinline__ void gemm_store_stats(float acc[8][4], const float* __restrict__ bias,
                                                 float* __restrict__ y,
                                                 float* __restrict__ psum, float* __restrict__ psq,
                                                 int R0, int tr, int tc, int bid) {
  float bb[4];
#pragma unroll
  for (int j = 0; j < 4; ++j) bb[j] = bias[tc * 4 + j];
  float sum[4] = {0, 0, 0, 0}, sq[4] = {0, 0, 0, 0};
#pragma unroll
  for (int i = 0; i < 8; ++i) {
    float v[4];
#pragma unroll
    for (int j = 0; j < 4; ++j) {
      const float t = acc[i][j] + bb[j];
      v[j] = t;
      sum[j] += t;
      sq[j] = fmaf(t, t, sq[j]);
    }
    *(float4*)&y[((size_t)(R0 + tr + 16 * i)) * kC1 + tc * 4] =
        make_float4(v[0], v[1], v[2], v[3]);
  }
#pragma unroll
  for (int off = 1; off < 16; off <<= 1) {
#pragma unroll
    for (int j = 0; j < 4; ++j) {
      sum[j] += __shfl_xor(sum[j], off, 64);
      sq[j]  += __shfl_xor(sq[j], off, 64);
    }
  }
  if (tr == 0) {
    *(float4*)&psum[(size_t)bid * kC1 + tc * 4] = make_float4(sum[0], sum[1], sum[2], sum[3]);
    *(float4*)&psq[(size_t)bid * kC1 + tc * 4]  = make_float4(sq[0], sq[1], sq[2], sq[3]);
  }
}

// ---------------- Layer 1: fused gather + GEMM(K=67->68, N=64) ---------------
__global__ __launch_bounds__(256) void gemm1_kernel(
    const float* __restrict__ xyz, const float* __restrict__ points,
    const float* __restrict__ newxyz, const int* __restrict__ gidx,
    const float* __restrict__ W, const float* __restrict__ bias,
    float* __restrict__ y, float* __restrict__ psum, float* __restrict__ psq) {
  __shared__ float xs[kTileR][kC0P];
  __shared__ float wl[kC1][kC0P];
  __shared__ int   gl[kTileR];
  __shared__ float nx[4][3];
  const int tid = threadIdx.x;
  const int R0  = blockIdx.x * kTileR;
  const int b   = R0 >> 15;          // 32768 rows per batch
  const int G0  = R0 >> 5;           // global group id base (4 groups per tile)
  if (tid < kTileR) gl[tid] = gidx[R0 + tid];
  if (tid >= 128 && tid < 140) {
    const int q = (tid - 128) / 3, c = (tid - 128) % 3;
    nx[q][c] = newxyz[(size_t)(G0 + q) * 3 + c];
  }
  // Stage W reordered: c'=0..2 -> W[:,0..2], c'=3 -> 0, c'>=4 -> W[:,c'-1]
  for (int i = tid; i < kC1 * kC0P; i += 256) {
    const int o = i / kC0P, c = i % kC0P;
    float v;
    if (c < 3)       v = W[o * kC0 + c];
    else if (c == 3) v = 0.0f;
    else             v = W[o * kC0 + (c - 1)];
    wl[o][c] = v;
  }
  __syncthreads();
  // Gather-stage xs: [dx,dy,dz,0, p0..p63]
  for (int i = tid; i < kTileR * 17; i += 256) {
    const int r = i / 17, q = i % 17;
    const int n = gl[r];
    if (q == 0) {
      const float* xp = xyz + ((size_t)(b * kN + n)) * 3;
      const int sq4 = r >> 5;
      xs[r][0] = __fsub_rn(xp[0], nx[sq4][0]);
      xs[r][1] = __fsub_rn(xp[1], nx[sq4][1]);
      xs[r][2] = __fsub_rn(xp[2], nx[sq4][2]);
      xs[r][3] = 0.0f;
    } else {
      const float4 p = *(const float4*)(points + ((size_t)(b * kN + n)) * kInCh + (q - 1) * 4);
      *(float4*)&xs[r][q * 4] = p;
    }
  }
  __syncthreads();
  const int tr = tid & 15, tc = tid >> 4;
  float acc[8][4];
  gemm_compute<kC0P>(xs, wl, tr, tc, acc);
  gemm_store_stats(acc, bias, y, psum, psq, R0, tr, tc, blockIdx.x);
}

// ---------------- Layer 2: GEMM(K=64, N=64), BN1+ReLU fused on input --------
__global__ __launch_bounds__(256) void gemm2_kernel(
    const float* __restrict__ x, const float* __restrict__ W, const float* __restrict__ bias,
    const float* __restrict__ a, const float* __restrict__ sft,
    float* __restrict__ y, float* __restrict__ psum, float* __restrict__ psq) {
  __shared__ float xs[kTileR][kC0P];
  __shared__ float wl[kC1][kC0P];
  const int tid = threadIdx.x;
  const int R0  = blockIdx.x * kTileR;
  for (int i = tid; i < kTileR * 16; i += 256) {
    const int r = i >> 4, cq = i & 15;
    float4 v = *(const float4*)&x[((size_t)(R0 + r)) * kC1 + cq * 4];
    const float4 av = *(const float4*)&a[cq * 4];
    const float4 sv = *(const float4*)&sft[cq * 4];
    v.x = fmaxf(fmaf(av.x, v.x, sv.x), 0.0f);
    v.y = fmaxf(fmaf(av.y, v.y, sv.y), 0.0f);
    v.z = fmaxf(fmaf(av.z, v.z, sv.z), 0.0f);
    v.w = fmaxf(fmaf(av.w, v.w, sv.w), 0.0f);
    *(float4*)&xs[r][cq * 4] = v;
  }
  for (int i = tid; i < kC1 * 16; i += 256) {
    const int o = i >> 4, cq = i & 15;
    *(float4*)&wl[o][cq * 4] = *(const float4*)&W[(size_t)o * kC1 + cq * 4];
  }
  __syncthreads();
  const int tr = tid & 15, tc = tid >> 4;
  float acc[8][4];
  gemm_compute<kC1>(xs, wl, tr, tc, acc);
  gemm_store_stats(acc, bias, y, psum, psq, R0, tr, tc, blockIdx.x);
}

// ---------------- Layer 3 pass A: stats only (no y3 store) -------------------
__global__ __launch_bounds__(256) void gemm3a_kernel(
    const float* __restrict__ x, const float* __restrict__ W, const float* __restrict__ bias,
    const float* __restrict__ a, const float* __restrict__ sft,
    float* __restrict__ psum, float* __restrict__ psq) {
  __shared__ float xs[kTileR][kC0P];
  __shared__ float wl[kC1][kC0P];
  const int tid = threadIdx.x;
  const int R0  = blockIdx.x * kTileR;
  for (int i = tid; i < kTileR * 16; i += 256) {
    const int r = i >> 4, cq = i & 15;
    float4 v = *(const float4*)&x[((size_t)(R0 + r)) * kC1 + cq * 4];
    const float4 av = *(const float4*)&a[cq * 4];
    const float4 sv = *(const float4*)&sft[cq * 4];
    v.x = fmaxf(fmaf(av.x, v.x, sv.x), 0.0f);
    v.y = fmaxf(fmaf(av.y, v.y, sv.y), 0.0f);
    v.z = fmaxf(fmaf(av.z, v.z, sv.z), 0.0f);
    v.w = fmaxf(fmaf(av.w, v.w, sv.w), 0.0f);
    *(float4*)&xs[r][cq * 4] = v;
  }
  const int tr = tid & 15, tc = tid >> 4;
  for (int cp = 0; cp < 2; ++cp) {
    __syncthreads();
    for (int i = tid; i < kC1 * 16; i += 256) {
      const int o = i >> 4, cq = i & 15;
      *(float4*)&wl[o][cq * 4] = *(const float4*)&W[((size_t)(cp * 64 + o)) * kC1 + cq * 4];
    }
    __syncthreads();
    float acc[8][4];
    gemm_compute<kC1>(xs, wl, tr, tc, acc);
    float bb[4];
#pragma unroll
    for (int j = 0; j < 4; ++j) bb[j] = bias[cp * 64 + tc * 4 + j];
    float sum[4] = {0, 0, 0, 0}, sq[4] = {0, 0, 0, 0};
#pragma unroll
    for (int i = 0; i < 8; ++i)
#pragma unroll
      for (int j = 0; j < 4; ++j) {
        const float t = acc[i][j] + bb[j];
        sum[j] += t;
        sq[j] = fmaf(t, t, sq[j]);
      }
#pragma unroll
    for (int off = 1; off < 16; off <<= 1) {
#pragma unroll
      for (int j = 0; j < 4; ++j) {
        sum[j] += __shfl_xor(sum[j], off, 64);
        sq[j]  += __shfl_xor(sq[j], off, 64);
      }
    }
    if (tr == 0) {
      *(float4*)&psum[(size_t)blockIdx.x * kC3 + cp * 64 + tc * 4] =
          make_float4(sum[0], sum[1], sum[2], sum[3]);
      *(float4*)&psq[(size_t)blockIdx.x * kC3 + cp * 64 + tc * 4] =
          make_float4(sq[0], sq[1], sq[2], sq[3]);
    }
  }
}

// ---------------- Layer 3 pass B: recompute + BN3 + ReLU + max over k -------
__global__ __launch_bounds__(256) void gemm3b_kernel(
    const float* __restrict__ x, const float* __restrict__ W, const float* __restrict__ bias,
    const float* __restrict__ a2, const float* __restrict__ s2,
    const float* __restrict__ a3, const float* __restrict__ s3,
    float* __restrict__ outp) {
  __shared__ float xs[kTileR][kC0P];
  __shared__ float wl[kC1][kC0P];
  const int tid = threadIdx.x;
  const int R0  = blockIdx.x * kTileR;
  const int G0  = R0 >> 5;
  for (int i = tid; i < kTileR * 16; i += 256) {
    const int r = i >> 4, cq = i & 15;
    float4 v = *(const float4*)&x[((size_t)(R0 + r)) * kC1 + cq * 4];
    const float4 av = *(const float4*)&a2[cq * 4];
    const float4 sv = *(const float4*)&s2[cq * 4];
    v.x = fmaxf(fmaf(av.x, v.x, sv.x), 0.0f);
    v.y = fmaxf(fmaf(av.y, v.y, sv.y), 0.0f);
    v.z = fmaxf(fmaf(av.z, v.z, sv.z), 0.0f);
    v.w = fmaxf(fmaf(av.w, v.w, sv.w), 0.0f);
    *(float4*)&xs[r][cq * 4] = v;
  }
  const int tr = tid & 15, tc = tid >> 4;
  for (int cp = 0; cp < 2; ++cp) {
    __syncthreads();
    for (int i = tid; i < kC1 * 16; i += 256) {
      const int o = i >> 4, cq = i & 15;
      *(float4*)&wl[o][cq * 4] = *(const float4*)&W[((size_t)(cp * 64 + o)) * kC1 + cq * 4];
    }
    __syncthreads();
    float acc[8][4];
    gemm_compute<kC1>(xs, wl, tr, tc, acc);
    float bb[4], av3[4], sv3[4];
#pragma unroll
    for (int j = 0; j < 4; ++j) {
      const int col = cp * 64 + tc * 4 + j;
      bb[j]  = bias[col];
      av3[j] = a3[col];
      sv3[j] = s3[col];
    }
    float mm[4][4];
#pragma unroll
    for (int i = 0; i < 8; ++i) {
      const int s4 = i >> 1;
#pragma unroll
      for (int j = 0; j < 4; ++j) {
        const float t = acc[i][j] + bb[j];
        const float v = fmaxf(fmaf(av3[j], t, sv3[j]), 0.0f);
        mm[s4][j] = (i & 1) ? fmaxf(mm[s4][j], v) : v;
      }
    }
#pragma unroll
    for (int off = 1; off < 16; off <<= 1)
#pragma unroll
      for (int s4 = 0; s4 < 4; ++s4)
#pragma unroll
        for (int j = 0; j < 4; ++j)
          mm[s4][j] = fmaxf(mm[s4][j], __shfl_xor(mm[s4][j], off, 64));
    if (tr == 0) {
#pragma unroll
      for (int s4 = 0; s4 < 4; ++s4) {
        *(float4*)&outp[(size_t)(G0 + s4) * kC3 + cp * 64 + tc * 4] =
            make_float4(mm[s4][0], mm[s4][1], mm[s4][2], mm[s4][3]);
      }
    }
  }
}

// ---------------- BN stats finalize ------------------------------------------
__global__ void finalize_kernel(const float* __restrict__ psum, const float* __restrict__ psq,
                                const float* __restrict__ g, const float* __restrict__ be,
                                float* __restrict__ a, float* __restrict__ s,
                                int nch, int nblocks) {
  const int c = threadIdx.x;
  if (c >= nch) return;
  float sum = 0.f, sq = 0.f;
  for (int i = 0; i < nblocks; ++i) {
    sum += psum[(size_t)i * nch + c];
    sq  += psq[(size_t)i * nch + c];
  }
  const float inv = 1.0f / (float)kRows;
  const float mu  = sum * inv;
  const float var = sq * inv - mu * mu;
  const float rs  = 1.0f / sqrtf(var + 1e-5f);
  const float av  = g[c] * rs;
  a[c] = av;
  s[c] = be[c] - av * mu;
}

}  // namespace

extern "C" void kernel_launch(void* const* d_in, const int* in_sizes, int n_in,
                              void* d_out, int out_size, void* d_ws, size_t ws_size,
                              hipStream_t stream) {
  const float* xyz    = (const float*)d_in[0];
  const float* points = (const float*)d_in[1];
  const float* W0  = (const float*)d_in[2];
  const float* b0  = (const float*)d_in[3];
  const float* g0  = (const float*)d_in[4];
  const float* be0 = (const float*)d_in[5];
  const float* W1  = (const float*)d_in[6];
  const float* b1  = (const float*)d_in[7];
  const float* g1  = (const float*)d_in[8];
  const float* be1 = (const float*)d_in[9];
  const float* W2  = (const float*)d_in[10];
  const float* b2  = (const float*)d_in[11];
  const float* g2  = (const float*)d_in[12];
  const float* be2 = (const float*)d_in[13];

  float* out      = (float*)d_out;
  float* newxyz   = out;            // 8*1024*3 = 24576 floats
  float* newpts   = out + 24576;    // 8*1024*128

  char* wsb = (char*)d_ws;
  int*   gidx = (int*)wsb;                              // 1 MiB
  float* a1 = (float*)(wsb + (1u << 20));
  float* s1 = a1 + 128;
  float* a2 = s1 + 128;
  float* s2 = a2 + 128;
  float* a3 = s2 + 128;
  float* s3 = a3 + 128;
  float* psum = (float*)(wsb + 2u * (1u << 20));        // 1 MiB
  float* psq  = (float*)(wsb + 3u * (1u << 20));        // 1 MiB
  float* y1 = (float*)(wsb + 4u * (1u << 20));          // 64 MiB
  float* y2 = (float*)(wsb + 68u * (1u << 20));         // 64 MiB

  fps_kernel<<<kNB, 1024, 0, stream>>>(xyz, newxyz);
  ballq_kernel<<<(kNB * kS) / 4, 256, 0, stream>>>(xyz, newxyz, gidx);
  gemm1_kernel<<<kGemmBlocks, 256, 0, stream>>>(xyz, points, newxyz, gidx, W0, b0, y1, psum, psq);
  finalize_kernel<<<1, 64, 0, stream>>>(psum, psq, g0, be0, a1, s1, 64, kGemmBlocks);
  gemm2_kernel<<<kGemmBlocks, 256, 0, stream>>>(y1, W1, b1, a1, s1, y2, psum, psq);
  finalize_kernel<<<1, 64, 0, stream>>>(psum, psq, g1, be1, a2, s2, 64, kGemmBlocks);
  gemm3a_kernel<<<kGemmBlocks, 256, 0, stream>>>(y2, W2, b2, a2, s2, psum, psq);
  finalize_kernel<<<1, 128, 0, stream>>>(psum, psq, g2, be2, a3, s3, 128, kGemmBlocks);
  gemm3b_kernel<<<kGemmBlocks, 256, 0, stream>>>(y2, W2, b2, a2, s2, a3, s3, newpts);
}